// Round 4
// baseline (390.302 us; speedup 1.0000x reference)
//
#include <hip/hip_runtime.h>
#include <hip/hip_bf16.h>
#include <math.h>

// MoE: B=8,N=1024,E=1024,H=1536,X=8,K=2. Routed (top-2 only) bf16 MFMA impl.
// R9 (resubmit; R3 bench was an infra failure, container never ran):
//     deepen GEMM prefetch. All 8 global_load_lds of K-tile t+1 issue at the
//     seam of iter t (the moment buf c^1 is free), so the next seam's counted
//     vmcnt(8) waits on loads ~1 full iteration old (was: last B-loads issued
//     1-2 phases before the wait -> per-iter HBM/L3-latency stall).
//     Phases are now pure {ds_read | lgkmcnt | setprio MFMA | barrier}.
//     MT=8: gemm1 grid 384 (no dead blocks), gemm2 grid 256 (1 full round).
#define T_TOK 8192
#define E_DIM 1024
#define H_DIM 1536
#define X_EXP 8

typedef unsigned short u16;
typedef unsigned int u32;

typedef __attribute__((ext_vector_type(8))) short frag_ab;   // 8 bf16 (4 VGPRs)
typedef __attribute__((ext_vector_type(4))) float frag_cd;   // 4 fp32 acc

__device__ __forceinline__ u16 f2bf(float f) {
  u32 u = __float_as_uint(f);
  u32 r = u + 0x7fffu + ((u >> 16) & 1u);   // round-to-nearest-even
  return (u16)(r >> 16);
}
__device__ __forceinline__ float bf2f(u16 h) {
  return __uint_as_float(((u32)h) << 16);
}

__device__ __forceinline__ void gl2lds16(const u16* g, u16* l) {
  // async global->LDS, 16B per lane; LDS dst must be wave-uniform base + lane*16
  __builtin_amdgcn_global_load_lds((const __attribute__((address_space(1))) void*)g,
                                   (__attribute__((address_space(3))) void*)l,
                                   16, 0, 0);
}

// ---- workspace layout (bytes) ----
static const size_t O_T2    = 4096;                                   // T*2 ints
static const size_t O_CLIST = O_T2 + (size_t)T_TOK * 2 * 4;           // 69632
static const size_t O_XB    = O_CLIST + (size_t)T_TOK * 2 * 4;        // 135168
static const size_t O_W1T   = O_XB + (size_t)T_TOK * E_DIM * 2;       // 16912384
static const size_t O_W2T   = O_W1T + (size_t)X_EXP * E_DIM * H_DIM * 2; // 42078208
static const size_t O_HB    = O_W2T + (size_t)X_EXP * E_DIM * H_DIM * 2; // 67244032
// end = 117575680 bytes (~112 MiB). y overlays xb+w1t (dead after gemm1).
static const size_t O_Y     = O_XB;

// ---- fused prep ----
// blocks 0..255: router+convert, 32 tokens each (8 chunks of 4).
// blocks 256..6399: W1/W2 transpose+convert.
__global__ __launch_bounds__(256) void k_prep(const float* __restrict__ x,
                                              const float* __restrict__ Wr,
                                              const float* __restrict__ br,
                                              const float* __restrict__ W1,
                                              const float* __restrict__ W2,
                                              float* __restrict__ out,
                                              u16* __restrict__ xb,
                                              u16* __restrict__ w1t,
                                              u16* __restrict__ w2t,
                                              int* __restrict__ t2,
                                              int* __restrict__ counts) {
  __shared__ union {
    float tile[64][65];
    struct { float red[4][4][8]; int cnt[8]; } r;
  } sm;
  int blk = blockIdx.x;
  int tid = threadIdx.x;

  if (blk < 256) {
    // thread owns elems tid*4..tid*4+3 (fixed across tokens); Wr rows in regs
    float4 wq[8];
    {
      const float4* wr4 = (const float4*)Wr + (size_t)tid * 8;
#pragma unroll
      for (int j = 0; j < 8; j++) wq[j] = wr4[j];
    }
    if (tid < 8) sm.r.cnt[tid] = 0;
    __syncthreads();

    int lane = tid & 63, wave = tid >> 6;
    for (int chunk = 0; chunk < 8; chunk++) {
      int tbase = blk * 32 + chunk * 4;      // first of 4 tokens this chunk
      float acc[4][8];
#pragma unroll
      for (int it = 0; it < 4; it++)
#pragma unroll
        for (int e = 0; e < 8; e++) acc[it][e] = 0.f;

#pragma unroll
      for (int it = 0; it < 4; it++) {
        size_t base = (size_t)(tbase + it) * 1024 + tid * 4;
        float4 v = *(const float4*)(x + base);
        ushort4 o;
        o.x = f2bf(v.x); o.y = f2bf(v.y); o.z = f2bf(v.z); o.w = f2bf(v.w);
        *(ushort4*)(xb + base) = o;
        float xv[4] = {v.x, v.y, v.z, v.w};
#pragma unroll
        for (int j = 0; j < 4; j++) {
#pragma unroll
          for (int e = 0; e < 8; e++) {
            float4 q = wq[j * 2 + (e >> 2)];
            float wv = (e & 3) == 0 ? q.x : (e & 3) == 1 ? q.y : (e & 3) == 2 ? q.z : q.w;
            acc[it][e] += xv[j] * wv;
          }
        }
      }
#pragma unroll
      for (int off = 32; off; off >>= 1)
#pragma unroll
        for (int it = 0; it < 4; it++)
#pragma unroll
          for (int e = 0; e < 8; e++)
            acc[it][e] += __shfl_down(acc[it][e], off);
      if (lane == 0) {
#pragma unroll
        for (int it = 0; it < 4; it++)
#pragma unroll
          for (int e = 0; e < 8; e++) sm.r.red[wave][it][e] = acc[it][e];
      }
      __syncthreads();
      if (tid < 4) {
        int t = tbase + tid;
        float lg[8];
#pragma unroll
        for (int e = 0; e < 8; e++)
          lg[e] = sm.r.red[0][tid][e] + sm.r.red[1][tid][e] + sm.r.red[2][tid][e] + sm.r.red[3][tid][e] + br[e];
        int i0 = 0; float v0 = lg[0];
#pragma unroll
        for (int e = 1; e < 8; e++) if (lg[e] > v0) { v0 = lg[e]; i0 = e; }
        int i1 = -1; float v1 = -3.4e38f;
#pragma unroll
        for (int e = 0; e < 8; e++) if (e != i0 && lg[e] > v1) { v1 = lg[e]; i1 = e; }
        out[(size_t)T_TOK * E_DIM + (size_t)t * 2 + 0] = (float)i0;
        out[(size_t)T_TOK * E_DIM + (size_t)t * 2 + 1] = (float)i1;
        t2[t * 2 + 0] = i0;
        t2[t * 2 + 1] = i1;
        atomicAdd(&sm.r.cnt[i0], 1);
        atomicAdd(&sm.r.cnt[i1], 1);
      }
      __syncthreads();                      // red reused next chunk
    }
    if (tid < 8) atomicAdd(&counts[tid], sm.r.cnt[tid]);
  } else {
    const float* src; u16* dst; int R, C, bx, by, e;
    if (blk < 256 + 3072) {
      int l = blk - 256;            // W1: R=E=1024, C=H=1536, grid (24,16,8)
      bx = l % 24; by = (l / 24) % 16; e = l / 384;
      R = E_DIM; C = H_DIM;
      src = W1 + (size_t)e * R * C; dst = w1t + (size_t)e * R * C;
    } else {
      int l = blk - (256 + 3072);   // W2: R=H=1536, C=E=1024, grid (16,24,8)
      bx = l % 16; by = (l / 16) % 24; e = l / 384;
      R = H_DIM; C = E_DIM;
      src = W2 + (size_t)e * R * C; dst = w2t + (size_t)e * R * C;
    }
    int c0 = bx * 64, r0 = by * 64;
    int tc = tid & 15, tr = tid >> 4;
#pragma unroll
    for (int i = 0; i < 4; i++) {
      int rr = tr + i * 16;
      float4 v = *(const float4*)(src + (size_t)(r0 + rr) * C + c0 + tc * 4);
      sm.tile[rr][tc * 4 + 0] = v.x;
      sm.tile[rr][tc * 4 + 1] = v.y;
      sm.tile[rr][tc * 4 + 2] = v.z;
      sm.tile[rr][tc * 4 + 3] = v.w;
    }
    __syncthreads();
#pragma unroll
    for (int i = 0; i < 4; i++) {
      int hh = tr + i * 16;
      ushort4 o;
      o.x = f2bf(sm.tile[tc * 4 + 0][hh]);
      o.y = f2bf(sm.tile[tc * 4 + 1][hh]);
      o.z = f2bf(sm.tile[tc * 4 + 2][hh]);
      o.w = f2bf(sm.tile[tc * 4 + 3][hh]);
      *(ushort4*)(dst + (size_t)(c0 + hh) * R + r0 + tc * 4) = o;
    }
  }
}

// fills clist and packs compact slot into t2: t2[t*2+k] = e | (slot<<3)
// Two-level ranking: LDS atomics for within-block rank, one global atomic
// per expert per block for the base. Slot order within an expert is an
// arbitrary bijection (nothing downstream depends on order).
__global__ __launch_bounds__(256) void k_fill(int* __restrict__ t2,
                                              const int* __restrict__ counts,
                                              int* __restrict__ curs,
                                              int* __restrict__ clist) {
  __shared__ int c8[8], base8[8];
  int tid = threadIdx.x;
  if (tid < 8) c8[tid] = 0;
  __syncthreads();

  int t = blockIdx.x * 256 + tid;
  int e0 = t2[t * 2 + 0] & 7;
  int e1 = t2[t * 2 + 1] & 7;
  int r0 = atomicAdd(&c8[e0], 1);
  int r1 = atomicAdd(&c8[e1], 1);
  __syncthreads();
  if (tid < 8) base8[tid] = atomicAdd(&curs[tid], c8[tid]);
  __syncthreads();

  int offs[8];
  {
    int run = 0;
#pragma unroll
    for (int e = 0; e < 8; e++) { offs[e] = run; run += counts[e]; }
  }
  int s0 = offs[e0] + base8[e0] + r0;
  int s1 = offs[e1] + base8[e1] + r1;
  clist[s0] = t;
  clist[s1] = t;
  t2[t * 2 + 0] = e0 | (s0 << 3);
  t2[t * 2 + 1] = e1 | (s1 << 3);
}

// ---- 256x256 8-wave phase-interleaved GEMM (shared by gemm1/gemm2) ----
// A: [rows][KD] bf16 (gathered via clist when GATHER), B: [e][CN][KD] bf16 (B^T),
// C: [rows][CN] bf16. GELU => +bias then tanh-gelu (gemm1 epilogue).
// 512 thr = 8 waves (2M x 4N); per-wave out 128x64 = acc[8][4] frag_cd.
// LDS: lA[2][256*64] + lB[2][256*64] = 128 KiB (dynamic), XOR-8 col-group
// swizzle applied on the *source* address, gl2lds dst linear (guide rule 21).
// Grid: 8 experts x MT(8) m-tiles x NTI; grid-stride m-loop for safety.

#define STG_A(cc, kk, ss) gl2lds16(gA[ss] + (kk), lA + (cc) * LDSTILE + ((ss) * 512 + tid) * 8)
#define STG_B(cc, kk, ss) gl2lds16(gB[ss] + (kk), lB + (cc) * LDSTILE + ((ss) * 512 + tid) * 8)
#define LDA8(qm) { const u16* cA_ = lA + c * LDSTILE; \
  _Pragma("unroll") for (int i_ = 0; i_ < 4; i_++) { \
    const u16* p_ = cA_ + (wm * 128 + ((qm) * 4 + i_) * 16 + mr) * 64; \
    Af[i_ * 2 + 0] = *(const frag_ab*)(p_ + g0); \
    Af[i_ * 2 + 1] = *(const frag_ab*)(p_ + g1); } }
#define LDB4(qn) { const u16* cB_ = lB + c * LDSTILE; \
  _Pragma("unroll") for (int j_ = 0; j_ < 2; j_++) { \
    const u16* p_ = cB_ + (wn * 64 + ((qn) * 2 + j_) * 16 + mr) * 64; \
    Bf[j_ * 2 + 0] = *(const frag_ab*)(p_ + g0); \
    Bf[j_ * 2 + 1] = *(const frag_ab*)(p_ + g1); } }
#define MMA16(qm, qn) { \
  _Pragma("unroll") for (int i_ = 0; i_ < 4; i_++) \
  _Pragma("unroll") for (int j_ = 0; j_ < 2; j_++) { \
    acc[(qm) * 4 + i_][(qn) * 2 + j_] = __builtin_amdgcn_mfma_f32_16x16x32_bf16(Af[i_ * 2 + 0], Bf[j_ * 2 + 0], acc[(qm) * 4 + i_][(qn) * 2 + j_], 0, 0, 0); \
    acc[(qm) * 4 + i_][(qn) * 2 + j_] = __builtin_amdgcn_mfma_f32_16x16x32_bf16(Af[i_ * 2 + 1], Bf[j_ * 2 + 1], acc[(qm) * 4 + i_][(qn) * 2 + j_], 0, 0, 0); } }
#define WAITLGKM do { asm volatile("s_waitcnt lgkmcnt(0)" ::: "memory"); \
  __builtin_amdgcn_sched_barrier(0); } while (0)

template<int KD, int CN, bool GELU, bool GATHER>
__global__ __launch_bounds__(512, 2) void k_gemm8(const u16* __restrict__ Ag,
                                                  const u16* __restrict__ Bw,
                                                  const float* __restrict__ bias,
                                                  u16* __restrict__ Cg,
                                                  const int* __restrict__ counts,
                                                  const int* __restrict__ clist) {
  constexpr int NTI = CN / 256;   // n-tiles
  constexpr int NKT = KD / 64;    // k-tiles
  constexpr int MT  = 8;          // m-tiles per expert in grid (stride loop)
  constexpr int LDSTILE = 256 * 64;
  int bid = blockIdx.x;
  int e = bid & 7;                // XCD-pinned expert
  int slot = bid >> 3;            // 0..MT*NTI-1
  int cnt = counts[e];
  int mt = slot / NTI;
  int n0 = (slot % NTI) * 256;
  int off = 0;
#pragma unroll
  for (int j = 0; j < 8; j++) off += (j < e) ? counts[j] : 0;

  int tid = threadIdx.x;
  int lane = tid & 63, wave = tid >> 6;
  int wm = wave >> 2, wn = wave & 3;

  extern __shared__ __align__(16) u16 sm8[];
  u16* lA = sm8;                   // [2][256*64]
  u16* lB = sm8 + 2 * LDSTILE;     // [2][256*64]

  int q = lane >> 4, mr = lane & 15;
  int g0 = (q ^ (mr & 7)) * 8;        // swizzled LDS col offsets (u16 units)
  int g1 = g0 ^ (4 * 8);

  for (int m0 = mt * 256; m0 < cnt; m0 += MT * 256) {
    // staging source pointers: 4 A-loads + 4 B-loads per K-tile; source
    // col-group pre-swizzled, LDS dst linear (guide rule 21).
    const u16* gA[4];
    const u16* gB[4];
#pragma unroll
    for (int s = 0; s < 4; s++) {
      int idx = s * 512 + tid;       // 0..2047
      int r = idx >> 3;              // 0..255
      int cg = (idx & 7) ^ (r & 7);  // swizzled global col group
      int mrow = m0 + r; if (mrow >= cnt) mrow = cnt - 1;
      size_t arow;
      if constexpr (GATHER) arow = (size_t)clist[off + mrow] * KD;
      else                  arow = (size_t)(off + mrow) * KD;
      gA[s] = Ag + arow + cg * 8;
      gB[s] = Bw + (size_t)e * CN * KD + (size_t)(n0 + r) * KD + cg * 8;
    }

    frag_cd acc[8][4] = {};
    frag_ab Af[8], Bf[4];

    // prologue: full K-tile 0 into buf 0
#pragma unroll
    for (int s = 0; s < 4; s++) STG_A(0, 0, s);
#pragma unroll
    for (int s = 0; s < 4; s++) STG_B(0, 0, s);

#pragma unroll 2
    for (int t = 0; t < NKT; t++) {
      int c = t & 1;
      int kn = (t + 1) * 64;
      bool pf = (t + 1) < NKT;
      // seam: buf c^1 became free at the previous end-of-iter barrier.
      // Issue ALL 8 loads of tile t+1 NOW (prefetch depth = 1 full iter),
      // then counted-wait for tile t's 8 (the 8 new stay in flight).
      if (pf) {
        STG_A(c ^ 1, kn, 0); STG_A(c ^ 1, kn, 1);
        STG_A(c ^ 1, kn, 2); STG_A(c ^ 1, kn, 3);
        STG_B(c ^ 1, kn, 0); STG_B(c ^ 1, kn, 1);
        STG_B(c ^ 1, kn, 2); STG_B(c ^ 1, kn, 3);
        asm volatile("s_waitcnt vmcnt(8)" ::: "memory");
      } else {
        asm volatile("s_waitcnt vmcnt(0)" ::: "memory");
      }
      __builtin_amdgcn_s_barrier();
      // ph0: A[qm0] + B[qn0] reads | MFMA quadrant (0,0)
      LDA8(0); LDB4(0);
      WAITLGKM;
      __builtin_amdgcn_s_setprio(1);
      MMA16(0, 0);
      __builtin_amdgcn_s_setprio(0);
      __builtin_amdgcn_s_barrier();
      // ph1: B[qn1] reads | MFMA (0,1)
      LDB4(1);
      WAITLGKM;
      __builtin_amdgcn_s_setprio(1);
      MMA16(0, 1);
      __builtin_amdgcn_s_setprio(0);
      __builtin_amdgcn_s_barrier();
      // ph2: A[qm1] reads | MFMA (1,1)
      LDA8(1);
      WAITLGKM;
      __builtin_amdgcn_s_setprio(1);
      MMA16(1, 1);
      __builtin_amdgcn_s_setprio(0);
      __builtin_amdgcn_s_barrier();
      // ph3: B[qn0] re-read (keeps Bf at 16 VGPR) | MFMA (1,0)
      LDB4(0);
      WAITLGKM;
      __builtin_amdgcn_s_setprio(1);
      MMA16(1, 0);
      __builtin_amdgcn_s_setprio(0);
      __builtin_amdgcn_s_barrier();   // end-of-iter: closes all reads of buf c
    }

    // epilogue: C/D layout col=lane&15, row=(lane>>4)*4+reg
#pragma unroll
    for (int fi = 0; fi < 8; fi++) {
#pragma unroll
      for (int fj = 0; fj < 4; fj++) {
        int ng = n0 + wn * 64 + fj * 16 + mr;
        float bv = 0.f;
        if constexpr (GELU) bv = bias[e * CN + ng];
#pragma unroll
        for (int r = 0; r < 4; r++) {
          int mg = m0 + wm * 128 + fi * 16 + q * 4 + r;
          if (mg < cnt) {
            float v = acc[fi][fj][r];
            if constexpr (GELU) {
              v += bv;
              // tanh-GELU via sigmoid: v * sigma(1.5957691v + 0.0713548v^3)
              float z = v * (1.5957691216f + 0.0713548162f * v * v);
              v = v / (1.0f + __expf(-z));
            }
            Cg[(size_t)(off + mg) * CN + ng] = f2bf(v);
          }
        }
      }
    }
  }
}

// ---- combine: out[t] = 0.5*(y[slot0] + y[slot1] + b2[e0] + b2[e1]) ----
__global__ __launch_bounds__(256) void k_combine(const u16* __restrict__ y,
                                                 const float* __restrict__ b2,
                                                 const int* __restrict__ t2,
                                                 float* __restrict__ out) {
  int t = blockIdx.x;
  int c = threadIdx.x * 4;
  int v0 = t2[t * 2 + 0], v1 = t2[t * 2 + 1];
  int e0 = v0 & 7, s0 = v0 >> 3;
  int e1 = v1 & 7, s1 = v1 >> 3;
  ushort4 a = *(const ushort4*)(y + (size_t)s0 * E_DIM + c);
  ushort4 b = *(const ushort4*)(y + (size_t)s1 * E_DIM + c);
  float4 p0 = *(const float4*)(b2 + (size_t)e0 * E_DIM + c);
  float4 p1 = *(const float4*)(b2 + (size_t)e1 * E_DIM + c);
  float4 o;
  o.x = 0.5f * (bf2f(a.x) + bf2f(b.x) + p0.x + p1.x);
  o.y = 0.5f * (bf2f(a.y) + bf2f(b.y) + p0.y + p1.y);
  o.z = 0.5f * (bf2f(a.z) + bf2f(b.z) + p0.z + p1.z);
  o.w = 0.5f * (bf2f(a.w) + bf2f(b.w) + p0.w + p1.w);
  *(float4*)(out + (size_t)t * E_DIM + c) = o;
}

extern "C" void kernel_launch(void* const* d_in, const int* in_sizes, int n_in,
                              void* d_out, int out_size, void* d_ws, size_t ws_size,
                              hipStream_t stream) {
  (void)in_sizes; (void)n_in; (void)out_size; (void)ws_size;
  const float* x  = (const float*)d_in[0];
  const float* Wr = (const float*)d_in[1];
  const float* br = (const float*)d_in[2];
  const float* W1 = (const float*)d_in[3];
  const float* b1 = (const float*)d_in[4];
  const float* W2 = (const float*)d_in[5];
  const float* b2 = (const float*)d_in[6];
  float* out = (float*)d_out;
  char* ws = (char*)d_ws;

  int* meta  = (int*)ws;                  // counts@0, cursors@+16 ints
  int* t2    = (int*)(ws + O_T2);
  int* clist = (int*)(ws + O_CLIST);
  u16* xb    = (u16*)(ws + O_XB);
  u16* w1t   = (u16*)(ws + O_W1T);
  u16* w2t   = (u16*)(ws + O_W2T);
  u16* hb    = (u16*)(ws + O_HB);
  u16* y     = (u16*)(ws + O_Y);          // overlays xb+w1t (dead after gemm1)

  // opt-in to 128 KiB dynamic LDS (immediate host call, not graph-captured)
  static int attr_once = [] {
    (void)hipFuncSetAttribute(reinterpret_cast<const void*>(&k_gemm8<E_DIM, H_DIM, true, true>),
                              hipFuncAttributeMaxDynamicSharedMemorySize, 131072);
    (void)hipFuncSetAttribute(reinterpret_cast<const void*>(&k_gemm8<H_DIM, E_DIM, false, false>),
                              hipFuncAttributeMaxDynamicSharedMemorySize, 131072);
    return 0;
  }();
  (void)attr_once;

  hipMemsetAsync(ws, 0, 128, stream);     // zero counts + cursors

  k_prep<<<dim3(256 + 3072 + 3072), 256, 0, stream>>>(x, Wr, br, W1, W2, out, xb, w1t, w2t, t2, meta);
  k_fill<<<dim3(T_TOK / 256), 256, 0, stream>>>(t2, meta, meta + 16, clist);
  // gemm1: M=cnt[e] (~2048 -> 8 m-tiles), N=1536 (6 n-tiles), K=1024
  k_gemm8<E_DIM, H_DIM, true, true><<<dim3(8 * 8 * 6), 512, 131072, stream>>>(
      xb, w1t, b1, hb, meta, clist);
  // gemm2: N=1024 (4 n-tiles), K=1536
  k_gemm8<H_DIM, E_DIM, false, false><<<dim3(8 * 8 * 4), 512, 131072, stream>>>(
      hb, w2t, nullptr, y, meta, nullptr);
  k_combine<<<dim3(T_TOK), 256, 0, stream>>>(y, b2, t2, out);
}

// Round 5
// 369.111 us; speedup vs baseline: 1.0574x; 1.0574x over previous
//
#include <hip/hip_runtime.h>
#include <hip/hip_bf16.h>
#include <math.h>

// MoE: B=8,N=1024,E=1024,H=1536,X=8,K=2. Routed (top-2 only) bf16 MFMA impl.
// R10: (a) GEMM staging reverted to R7's proven spread-issue + vmcnt(2);
//      barrier moved BETWEEN ds_reads and lgkmcnt(0) (m201 pattern) so phase
//      p+1's reads overlap other waves' MFMA(p) and drain under the barrier.
//      (b) k_prep transpose: in-register 4x4 transpose, bf16 LDS [64][76],
//      ds ops 32->6 per thread, 16B global stores.
#define T_TOK 8192
#define E_DIM 1024
#define H_DIM 1536
#define X_EXP 8

typedef unsigned short u16;
typedef unsigned int u32;

typedef __attribute__((ext_vector_type(8))) short frag_ab;   // 8 bf16 (4 VGPRs)
typedef __attribute__((ext_vector_type(4))) float frag_cd;   // 4 fp32 acc

__device__ __forceinline__ u16 f2bf(float f) {
  u32 u = __float_as_uint(f);
  u32 r = u + 0x7fffu + ((u >> 16) & 1u);   // round-to-nearest-even
  return (u16)(r >> 16);
}
__device__ __forceinline__ float bf2f(u16 h) {
  return __uint_as_float(((u32)h) << 16);
}

__device__ __forceinline__ void gl2lds16(const u16* g, u16* l) {
  // async global->LDS, 16B per lane; LDS dst must be wave-uniform base + lane*16
  __builtin_amdgcn_global_load_lds((const __attribute__((address_space(1))) void*)g,
                                   (__attribute__((address_space(3))) void*)l,
                                   16, 0, 0);
}

// ---- workspace layout (bytes) ----
static const size_t O_T2    = 4096;                                   // T*2 ints
static const size_t O_CLIST = O_T2 + (size_t)T_TOK * 2 * 4;           // 69632
static const size_t O_XB    = O_CLIST + (size_t)T_TOK * 2 * 4;        // 135168
static const size_t O_W1T   = O_XB + (size_t)T_TOK * E_DIM * 2;       // 16912384
static const size_t O_W2T   = O_W1T + (size_t)X_EXP * E_DIM * H_DIM * 2; // 42078208
static const size_t O_HB    = O_W2T + (size_t)X_EXP * E_DIM * H_DIM * 2; // 67244032
// end = 117575680 bytes (~112 MiB). y overlays xb+w1t (dead after gemm1).
static const size_t O_Y     = O_XB;

// ---- fused prep ----
// blocks 0..255: router+convert, 32 tokens each (8 chunks of 4).
// blocks 256..6399: W1/W2 transpose+convert (in-register 4x4 transpose).
__global__ __launch_bounds__(256) void k_prep(const float* __restrict__ x,
                                              const float* __restrict__ Wr,
                                              const float* __restrict__ br,
                                              const float* __restrict__ W1,
                                              const float* __restrict__ W2,
                                              float* __restrict__ out,
                                              u16* __restrict__ xb,
                                              u16* __restrict__ w1t,
                                              u16* __restrict__ w2t,
                                              int* __restrict__ t2,
                                              int* __restrict__ counts) {
  __shared__ union {
    u16 lt[64][76];                                   // bf16 transpose tile
    struct { float red[4][4][8]; int cnt[8]; } r;
  } sm;
  int blk = blockIdx.x;
  int tid = threadIdx.x;

  if (blk < 256) {
    // thread owns elems tid*4..tid*4+3 (fixed across tokens); Wr rows in regs
    float4 wq[8];
    {
      const float4* wr4 = (const float4*)Wr + (size_t)tid * 8;
#pragma unroll
      for (int j = 0; j < 8; j++) wq[j] = wr4[j];
    }
    if (tid < 8) sm.r.cnt[tid] = 0;
    __syncthreads();

    int lane = tid & 63, wave = tid >> 6;
    for (int chunk = 0; chunk < 8; chunk++) {
      int tbase = blk * 32 + chunk * 4;      // first of 4 tokens this chunk
      float acc[4][8];
#pragma unroll
      for (int it = 0; it < 4; it++)
#pragma unroll
        for (int e = 0; e < 8; e++) acc[it][e] = 0.f;

#pragma unroll
      for (int it = 0; it < 4; it++) {
        size_t base = (size_t)(tbase + it) * 1024 + tid * 4;
        float4 v = *(const float4*)(x + base);
        ushort4 o;
        o.x = f2bf(v.x); o.y = f2bf(v.y); o.z = f2bf(v.z); o.w = f2bf(v.w);
        *(ushort4*)(xb + base) = o;
        float xv[4] = {v.x, v.y, v.z, v.w};
#pragma unroll
        for (int j = 0; j < 4; j++) {
#pragma unroll
          for (int e = 0; e < 8; e++) {
            float4 q = wq[j * 2 + (e >> 2)];
            float wv = (e & 3) == 0 ? q.x : (e & 3) == 1 ? q.y : (e & 3) == 2 ? q.z : q.w;
            acc[it][e] += xv[j] * wv;
          }
        }
      }
#pragma unroll
      for (int off = 32; off; off >>= 1)
#pragma unroll
        for (int it = 0; it < 4; it++)
#pragma unroll
          for (int e = 0; e < 8; e++)
            acc[it][e] += __shfl_down(acc[it][e], off);
      if (lane == 0) {
#pragma unroll
        for (int it = 0; it < 4; it++)
#pragma unroll
          for (int e = 0; e < 8; e++) sm.r.red[wave][it][e] = acc[it][e];
      }
      __syncthreads();
      if (tid < 4) {
        int t = tbase + tid;
        float lg[8];
#pragma unroll
        for (int e = 0; e < 8; e++)
          lg[e] = sm.r.red[0][tid][e] + sm.r.red[1][tid][e] + sm.r.red[2][tid][e] + sm.r.red[3][tid][e] + br[e];
        int i0 = 0; float v0 = lg[0];
#pragma unroll
        for (int e = 1; e < 8; e++) if (lg[e] > v0) { v0 = lg[e]; i0 = e; }
        int i1 = -1; float v1 = -3.4e38f;
#pragma unroll
        for (int e = 0; e < 8; e++) if (e != i0 && lg[e] > v1) { v1 = lg[e]; i1 = e; }
        out[(size_t)T_TOK * E_DIM + (size_t)t * 2 + 0] = (float)i0;
        out[(size_t)T_TOK * E_DIM + (size_t)t * 2 + 1] = (float)i1;
        t2[t * 2 + 0] = i0;
        t2[t * 2 + 1] = i1;
        atomicAdd(&sm.r.cnt[i0], 1);
        atomicAdd(&sm.r.cnt[i1], 1);
      }
      __syncthreads();                      // red reused next chunk
    }
    if (tid < 8) atomicAdd(&counts[tid], sm.r.cnt[tid]);
  } else {
    const float* src; u16* dst; int R, C, bx, by, e;
    if (blk < 256 + 3072) {
      int l = blk - 256;            // W1: R=E=1024, C=H=1536, grid (24,16,8)
      bx = l % 24; by = (l / 24) % 16; e = l / 384;
      R = E_DIM; C = H_DIM;
      src = W1 + (size_t)e * R * C; dst = w1t + (size_t)e * R * C;
    } else {
      int l = blk - (256 + 3072);   // W2: R=H=1536, C=E=1024, grid (16,24,8)
      bx = l % 16; by = (l / 16) % 24; e = l / 384;
      R = H_DIM; C = E_DIM;
      src = W2 + (size_t)e * R * C; dst = w2t + (size_t)e * R * C;
    }
    int c0 = bx * 64, r0 = by * 64;
    int tc = tid & 15, tr = tid >> 4;
    // load 4x4 fp32 block (rows r0+tr*4+j, cols c0+tc*4), transpose in regs,
    // write bf16 columns to LDS rows (c-index) with ds_write_b64.
    {
      float4 v0 = *(const float4*)(src + (size_t)(r0 + tr * 4 + 0) * C + c0 + tc * 4);
      float4 v1 = *(const float4*)(src + (size_t)(r0 + tr * 4 + 1) * C + c0 + tc * 4);
      float4 v2 = *(const float4*)(src + (size_t)(r0 + tr * 4 + 2) * C + c0 + tc * 4);
      float4 v3 = *(const float4*)(src + (size_t)(r0 + tr * 4 + 3) * C + c0 + tc * 4);
      ushort4 w;
      w.x = f2bf(v0.x); w.y = f2bf(v1.x); w.z = f2bf(v2.x); w.w = f2bf(v3.x);
      *(ushort4*)(&sm.lt[tc * 4 + 0][tr * 4]) = w;
      w.x = f2bf(v0.y); w.y = f2bf(v1.y); w.z = f2bf(v2.y); w.w = f2bf(v3.y);
      *(ushort4*)(&sm.lt[tc * 4 + 1][tr * 4]) = w;
      w.x = f2bf(v0.z); w.y = f2bf(v1.z); w.z = f2bf(v2.z); w.w = f2bf(v3.z);
      *(ushort4*)(&sm.lt[tc * 4 + 2][tr * 4]) = w;
      w.x = f2bf(v0.w); w.y = f2bf(v1.w); w.z = f2bf(v2.w); w.w = f2bf(v3.w);
      *(ushort4*)(&sm.lt[tc * 4 + 3][tr * 4]) = w;
    }
    __syncthreads();
    // read 16 consecutive r for one output row (c-index), 2x ds_read_b128,
    // store 2x16B to dst[(c0+cc)][r0+rs..rs+15]
    {
      int cc = tid >> 2, rs = (tid & 3) * 16;
      frag_ab a = *(const frag_ab*)(&sm.lt[cc][rs]);
      frag_ab b = *(const frag_ab*)(&sm.lt[cc][rs + 8]);
      u16* drow = dst + (size_t)(c0 + cc) * R + r0 + rs;
      *(frag_ab*)(drow) = a;
      *(frag_ab*)(drow + 8) = b;
    }
  }
}

// fills clist and packs compact slot into t2: t2[t*2+k] = e | (slot<<3)
// Two-level ranking: LDS atomics for within-block rank, one global atomic
// per expert per block for the base. Slot order within an expert is an
// arbitrary bijection (nothing downstream depends on order).
__global__ __launch_bounds__(256) void k_fill(int* __restrict__ t2,
                                              const int* __restrict__ counts,
                                              int* __restrict__ curs,
                                              int* __restrict__ clist) {
  __shared__ int c8[8], base8[8];
  int tid = threadIdx.x;
  if (tid < 8) c8[tid] = 0;
  __syncthreads();

  int t = blockIdx.x * 256 + tid;
  int e0 = t2[t * 2 + 0] & 7;
  int e1 = t2[t * 2 + 1] & 7;
  int r0 = atomicAdd(&c8[e0], 1);
  int r1 = atomicAdd(&c8[e1], 1);
  __syncthreads();
  if (tid < 8) base8[tid] = atomicAdd(&curs[tid], c8[tid]);
  __syncthreads();

  int offs[8];
  {
    int run = 0;
#pragma unroll
    for (int e = 0; e < 8; e++) { offs[e] = run; run += counts[e]; }
  }
  int s0 = offs[e0] + base8[e0] + r0;
  int s1 = offs[e1] + base8[e1] + r1;
  clist[s0] = t;
  clist[s1] = t;
  t2[t * 2 + 0] = e0 | (s0 << 3);
  t2[t * 2 + 1] = e1 | (s1 << 3);
}

// ---- 256x256 8-wave phase-interleaved GEMM (shared by gemm1/gemm2) ----
// A: [rows][KD] bf16 (gathered via clist when GATHER), B: [e][CN][KD] bf16 (B^T),
// C: [rows][CN] bf16. GELU => +bias then tanh-gelu (gemm1 epilogue).
// 512 thr = 8 waves (2M x 4N); per-wave out 128x64 = acc[8][4] frag_cd.
// LDS: lA[2][256*64] + lB[2][256*64] = 128 KiB (dynamic), XOR-8 col-group
// swizzle applied on the *source* address, gl2lds dst linear (guide rule 21).
// Per phase (m201 pattern): {ds_reads | stage issue | BARRIER | lgkmcnt(0) |
// setprio MFMA setprio} -- reads of phase p+1 overlap other waves' MFMA(p)
// and drain under the barrier. Stage issues spread 2/phase, seam vmcnt(2).
// Safety: all ds_reads in an iter hit buf c, all DMA writes hit c^1; stages
// into a buffer are only issued after the end-of-iter barrier that followed
// every wave's lgkmcnt(0)-guarded reads of it.

#define STG_A(cc, kk, ss) gl2lds16(gA[ss] + (kk), lA + (cc) * LDSTILE + ((ss) * 512 + tid) * 8)
#define STG_B(cc, kk, ss) gl2lds16(gB[ss] + (kk), lB + (cc) * LDSTILE + ((ss) * 512 + tid) * 8)
#define LDA8(qm) { const u16* cA_ = lA + c * LDSTILE; \
  _Pragma("unroll") for (int i_ = 0; i_ < 4; i_++) { \
    const u16* p_ = cA_ + (wm * 128 + ((qm) * 4 + i_) * 16 + mr) * 64; \
    Af[i_ * 2 + 0] = *(const frag_ab*)(p_ + g0); \
    Af[i_ * 2 + 1] = *(const frag_ab*)(p_ + g1); } }
#define LDB4(qn) { const u16* cB_ = lB + c * LDSTILE; \
  _Pragma("unroll") for (int j_ = 0; j_ < 2; j_++) { \
    const u16* p_ = cB_ + (wn * 64 + ((qn) * 2 + j_) * 16 + mr) * 64; \
    Bf[j_ * 2 + 0] = *(const frag_ab*)(p_ + g0); \
    Bf[j_ * 2 + 1] = *(const frag_ab*)(p_ + g1); } }
#define MMA16(qm, qn) { \
  _Pragma("unroll") for (int i_ = 0; i_ < 4; i_++) \
  _Pragma("unroll") for (int j_ = 0; j_ < 2; j_++) { \
    acc[(qm) * 4 + i_][(qn) * 2 + j_] = __builtin_amdgcn_mfma_f32_16x16x32_bf16(Af[i_ * 2 + 0], Bf[j_ * 2 + 0], acc[(qm) * 4 + i_][(qn) * 2 + j_], 0, 0, 0); \
    acc[(qm) * 4 + i_][(qn) * 2 + j_] = __builtin_amdgcn_mfma_f32_16x16x32_bf16(Af[i_ * 2 + 1], Bf[j_ * 2 + 1], acc[(qm) * 4 + i_][(qn) * 2 + j_], 0, 0, 0); } }
#define WAITLGKM do { asm volatile("s_waitcnt lgkmcnt(0)" ::: "memory"); \
  __builtin_amdgcn_sched_barrier(0); } while (0)

template<int KD, int CN, bool GELU, bool GATHER>
__global__ __launch_bounds__(512, 2) void k_gemm8(const u16* __restrict__ Ag,
                                                  const u16* __restrict__ Bw,
                                                  const float* __restrict__ bias,
                                                  u16* __restrict__ Cg,
                                                  const int* __restrict__ counts,
                                                  const int* __restrict__ clist) {
  constexpr int NTI = CN / 256;   // n-tiles
  constexpr int NKT = KD / 64;    // k-tiles
  constexpr int MT  = 8;          // m-tiles per expert in grid (stride loop)
  constexpr int LDSTILE = 256 * 64;
  int bid = blockIdx.x;
  int e = bid & 7;                // XCD-pinned expert
  int slot = bid >> 3;            // 0..MT*NTI-1
  int cnt = counts[e];
  int mt = slot / NTI;
  int n0 = (slot % NTI) * 256;
  int off = 0;
#pragma unroll
  for (int j = 0; j < 8; j++) off += (j < e) ? counts[j] : 0;

  int tid = threadIdx.x;
  int lane = tid & 63, wave = tid >> 6;
  int wm = wave >> 2, wn = wave & 3;

  extern __shared__ __align__(16) u16 sm8[];
  u16* lA = sm8;                   // [2][256*64]
  u16* lB = sm8 + 2 * LDSTILE;     // [2][256*64]

  int q = lane >> 4, mr = lane & 15;
  int g0 = (q ^ (mr & 7)) * 8;        // swizzled LDS col offsets (u16 units)
  int g1 = g0 ^ (4 * 8);

  for (int m0 = mt * 256; m0 < cnt; m0 += MT * 256) {
    // staging source pointers: 4 A-loads + 4 B-loads per K-tile; source
    // col-group pre-swizzled, LDS dst linear (guide rule 21).
    const u16* gA[4];
    const u16* gB[4];
#pragma unroll
    for (int s = 0; s < 4; s++) {
      int idx = s * 512 + tid;       // 0..2047
      int r = idx >> 3;              // 0..255
      int cg = (idx & 7) ^ (r & 7);  // swizzled global col group
      int mrow = m0 + r; if (mrow >= cnt) mrow = cnt - 1;
      size_t arow;
      if constexpr (GATHER) arow = (size_t)clist[off + mrow] * KD;
      else                  arow = (size_t)(off + mrow) * KD;
      gA[s] = Ag + arow + cg * 8;
      gB[s] = Bw + (size_t)e * CN * KD + (size_t)(n0 + r) * KD + cg * 8;
    }

    frag_cd acc[8][4] = {};
    frag_ab Af[8], Bf[4];

    // prologue: full K-tile 0 into buf 0
#pragma unroll
    for (int s = 0; s < 4; s++) STG_A(0, 0, s);
#pragma unroll
    for (int s = 0; s < 4; s++) STG_B(0, 0, s);

#pragma unroll 2
    for (int t = 0; t < NKT; t++) {
      int c = t & 1;
      int kn = (t + 1) * 64;
      bool pf = (t + 1) < NKT;
      // seam: issue first A-half of tile t+1 (buf c^1 closed by prior iter's
      // end barrier), then counted wait for tile t's 8 loads.
      if (pf) {
        STG_A(c ^ 1, kn, 0); STG_A(c ^ 1, kn, 1);
        asm volatile("s_waitcnt vmcnt(2)" ::: "memory");
      } else {
        asm volatile("s_waitcnt vmcnt(0)" ::: "memory");
      }
      __builtin_amdgcn_s_barrier();     // buf c fully staged for all waves
      // ph0: reads A[qm0]+B[qn0] | stage A-half1 | bar | wait | MFMA (0,0)
      LDA8(0); LDB4(0);
      if (pf) { STG_A(c ^ 1, kn, 2); STG_A(c ^ 1, kn, 3); }
      __builtin_amdgcn_s_barrier();
      WAITLGKM;
      __builtin_amdgcn_s_setprio(1);
      MMA16(0, 0);
      __builtin_amdgcn_s_setprio(0);
      // ph1: reads B[qn1] | stage B-half0 | bar | wait | MFMA (0,1)
      LDB4(1);
      if (pf) { STG_B(c ^ 1, kn, 0); STG_B(c ^ 1, kn, 1); }
      __builtin_amdgcn_s_barrier();
      WAITLGKM;
      __builtin_amdgcn_s_setprio(1);
      MMA16(0, 1);
      __builtin_amdgcn_s_setprio(0);
      // ph2: reads A[qm1] | stage B-half1 | bar | wait | MFMA (1,1)
      LDA8(1);
      if (pf) { STG_B(c ^ 1, kn, 2); STG_B(c ^ 1, kn, 3); }
      __builtin_amdgcn_s_barrier();
      WAITLGKM;
      __builtin_amdgcn_s_setprio(1);
      MMA16(1, 1);
      __builtin_amdgcn_s_setprio(0);
      // ph3: reads B[qn0] | bar | wait | MFMA (1,0)
      LDB4(0);
      __builtin_amdgcn_s_barrier();
      WAITLGKM;
      __builtin_amdgcn_s_setprio(1);
      MMA16(1, 0);
      __builtin_amdgcn_s_setprio(0);
      __builtin_amdgcn_s_barrier();   // end-of-iter: all reads of buf c done
    }

    // epilogue: C/D layout col=lane&15, row=(lane>>4)*4+reg
#pragma unroll
    for (int fi = 0; fi < 8; fi++) {
#pragma unroll
      for (int fj = 0; fj < 4; fj++) {
        int ng = n0 + wn * 64 + fj * 16 + mr;
        float bv = 0.f;
        if constexpr (GELU) bv = bias[e * CN + ng];
#pragma unroll
        for (int r = 0; r < 4; r++) {
          int mg = m0 + wm * 128 + fi * 16 + q * 4 + r;
          if (mg < cnt) {
            float v = acc[fi][fj][r];
            if constexpr (GELU) {
              v += bv;
              // tanh-GELU via sigmoid: v * sigma(1.5957691v + 0.0713548v^3)
              float z = v * (1.5957691216f + 0.0713548162f * v * v);
              v = v / (1.0f + __expf(-z));
            }
            Cg[(size_t)(off + mg) * CN + ng] = f2bf(v);
          }
        }
      }
    }
  }
}

// ---- combine: out[t] = 0.5*(y[slot0] + y[slot1] + b2[e0] + b2[e1]) ----
__global__ __launch_bounds__(256) void k_combine(const u16* __restrict__ y,
                                                 const float* __restrict__ b2,
                                                 const int* __restrict__ t2,
                                                 float* __restrict__ out) {
  int t = blockIdx.x;
  int c = threadIdx.x * 4;
  int v0 = t2[t * 2 + 0], v1 = t2[t * 2 + 1];
  int e0 = v0 & 7, s0 = v0 >> 3;
  int e1 = v1 & 7, s1 = v1 >> 3;
  ushort4 a = *(const ushort4*)(y + (size_t)s0 * E_DIM + c);
  ushort4 b = *(const ushort4*)(y + (size_t)s1 * E_DIM + c);
  float4 p0 = *(const float4*)(b2 + (size_t)e0 * E_DIM + c);
  float4 p1 = *(const float4*)(b2 + (size_t)e1 * E_DIM + c);
  float4 o;
  o.x = 0.5f * (bf2f(a.x) + bf2f(b.x) + p0.x + p1.x);
  o.y = 0.5f * (bf2f(a.y) + bf2f(b.y) + p0.y + p1.y);
  o.z = 0.5f * (bf2f(a.z) + bf2f(b.z) + p0.z + p1.z);
  o.w = 0.5f * (bf2f(a.w) + bf2f(b.w) + p0.w + p1.w);
  *(float4*)(out + (size_t)t * E_DIM + c) = o;
}

extern "C" void kernel_launch(void* const* d_in, const int* in_sizes, int n_in,
                              void* d_out, int out_size, void* d_ws, size_t ws_size,
                              hipStream_t stream) {
  (void)in_sizes; (void)n_in; (void)out_size; (void)ws_size;
  const float* x  = (const float*)d_in[0];
  const float* Wr = (const float*)d_in[1];
  const float* br = (const float*)d_in[2];
  const float* W1 = (const float*)d_in[3];
  const float* b1 = (const float*)d_in[4];
  const float* W2 = (const float*)d_in[5];
  const float* b2 = (const float*)d_in[6];
  float* out = (float*)d_out;
  char* ws = (char*)d_ws;

  int* meta  = (int*)ws;                  // counts@0, cursors@+16 ints
  int* t2    = (int*)(ws + O_T2);
  int* clist = (int*)(ws + O_CLIST);
  u16* xb    = (u16*)(ws + O_XB);
  u16* w1t   = (u16*)(ws + O_W1T);
  u16* w2t   = (u16*)(ws + O_W2T);
  u16* hb    = (u16*)(ws + O_HB);
  u16* y     = (u16*)(ws + O_Y);          // overlays xb+w1t (dead after gemm1)

  // opt-in to 128 KiB dynamic LDS (immediate host call, not graph-captured)
  static int attr_once = [] {
    (void)hipFuncSetAttribute(reinterpret_cast<const void*>(&k_gemm8<E_DIM, H_DIM, true, true>),
                              hipFuncAttributeMaxDynamicSharedMemorySize, 131072);
    (void)hipFuncSetAttribute(reinterpret_cast<const void*>(&k_gemm8<H_DIM, E_DIM, false, false>),
                              hipFuncAttributeMaxDynamicSharedMemorySize, 131072);
    return 0;
  }();
  (void)attr_once;

  hipMemsetAsync(ws, 0, 128, stream);     // zero counts + cursors

  k_prep<<<dim3(256 + 3072 + 3072), 256, 0, stream>>>(x, Wr, br, W1, W2, out, xb, w1t, w2t, t2, meta);
  k_fill<<<dim3(T_TOK / 256), 256, 0, stream>>>(t2, meta, meta + 16, clist);
  // gemm1: M=cnt[e] (~2048 -> 8 m-tiles), N=1536 (6 n-tiles), K=1024
  k_gemm8<E_DIM, H_DIM, true, true><<<dim3(8 * 8 * 6), 512, 131072, stream>>>(
      xb, w1t, b1, hb, meta, clist);
  // gemm2: N=1024 (4 n-tiles), K=1536
  k_gemm8<H_DIM, E_DIM, false, false><<<dim3(8 * 8 * 4), 512, 131072, stream>>>(
      hb, w2t, nullptr, y, meta, nullptr);
  k_combine<<<dim3(T_TOK), 256, 0, stream>>>(y, b2, t2, out);
}

// Round 6
// 351.680 us; speedup vs baseline: 1.1098x; 1.0496x over previous
//
#include <hip/hip_runtime.h>
#include <hip/hip_bf16.h>
#include <math.h>

// MoE: B=8,N=1024,E=1024,H=1536,X=8,K=2. Routed (top-2 only) bf16 MFMA impl.
// R11: GEMM inner loop collapsed to ONE __syncthreads per K-iter and a single
//      compiler-scheduled region (no manual lgkmcnt(0), no sched_barrier, no
//      setprio, no per-phase barriers). Three phase variants (R7/R9/R10) all
//      measured 105-115us @ ~20% MfmaUtil -> hand fences were serializing
//      LDS-reads against MFMA; hipcc's own partial lgkm waits overlap them.
//      B fragments read once per K-step (Bf[8], drops ph3 re-read: 28->24
//      ds_read_b128 per wave per iter). Staging spread kept (R7 best).
#define T_TOK 8192
#define E_DIM 1024
#define H_DIM 1536
#define X_EXP 8

typedef unsigned short u16;
typedef unsigned int u32;

typedef __attribute__((ext_vector_type(8))) short frag_ab;   // 8 bf16 (4 VGPRs)
typedef __attribute__((ext_vector_type(4))) float frag_cd;   // 4 fp32 acc

__device__ __forceinline__ u16 f2bf(float f) {
  u32 u = __float_as_uint(f);
  u32 r = u + 0x7fffu + ((u >> 16) & 1u);   // round-to-nearest-even
  return (u16)(r >> 16);
}
__device__ __forceinline__ float bf2f(u16 h) {
  return __uint_as_float(((u32)h) << 16);
}

__device__ __forceinline__ void gl2lds16(const u16* g, u16* l) {
  // async global->LDS, 16B per lane; LDS dst must be wave-uniform base + lane*16
  __builtin_amdgcn_global_load_lds((const __attribute__((address_space(1))) void*)g,
                                   (__attribute__((address_space(3))) void*)l,
                                   16, 0, 0);
}

// ---- workspace layout (bytes) ----
static const size_t O_T2    = 4096;                                   // T*2 ints
static const size_t O_CLIST = O_T2 + (size_t)T_TOK * 2 * 4;           // 69632
static const size_t O_XB    = O_CLIST + (size_t)T_TOK * 2 * 4;        // 135168
static const size_t O_W1T   = O_XB + (size_t)T_TOK * E_DIM * 2;       // 16912384
static const size_t O_W2T   = O_W1T + (size_t)X_EXP * E_DIM * H_DIM * 2; // 42078208
static const size_t O_HB    = O_W2T + (size_t)X_EXP * E_DIM * H_DIM * 2; // 67244032
// end = 117575680 bytes (~112 MiB). y overlays xb+w1t (dead after gemm1).
static const size_t O_Y     = O_XB;

// ---- fused prep ----
// blocks 0..255: router+convert, 32 tokens each (8 chunks of 4).
// blocks 256..6399: W1/W2 transpose+convert (in-register 4x4 transpose).
__global__ __launch_bounds__(256) void k_prep(const float* __restrict__ x,
                                              const float* __restrict__ Wr,
                                              const float* __restrict__ br,
                                              const float* __restrict__ W1,
                                              const float* __restrict__ W2,
                                              float* __restrict__ out,
                                              u16* __restrict__ xb,
                                              u16* __restrict__ w1t,
                                              u16* __restrict__ w2t,
                                              int* __restrict__ t2,
                                              int* __restrict__ counts) {
  __shared__ union {
    u16 lt[64][76];                                   // bf16 transpose tile
    struct { float red[4][4][8]; int cnt[8]; } r;
  } sm;
  int blk = blockIdx.x;
  int tid = threadIdx.x;

  if (blk < 256) {
    // thread owns elems tid*4..tid*4+3 (fixed across tokens); Wr rows in regs
    float4 wq[8];
    {
      const float4* wr4 = (const float4*)Wr + (size_t)tid * 8;
#pragma unroll
      for (int j = 0; j < 8; j++) wq[j] = wr4[j];
    }
    if (tid < 8) sm.r.cnt[tid] = 0;
    __syncthreads();

    int lane = tid & 63, wave = tid >> 6;
    for (int chunk = 0; chunk < 8; chunk++) {
      int tbase = blk * 32 + chunk * 4;      // first of 4 tokens this chunk
      float acc[4][8];
#pragma unroll
      for (int it = 0; it < 4; it++)
#pragma unroll
        for (int e = 0; e < 8; e++) acc[it][e] = 0.f;

#pragma unroll
      for (int it = 0; it < 4; it++) {
        size_t base = (size_t)(tbase + it) * 1024 + tid * 4;
        float4 v = *(const float4*)(x + base);
        ushort4 o;
        o.x = f2bf(v.x); o.y = f2bf(v.y); o.z = f2bf(v.z); o.w = f2bf(v.w);
        *(ushort4*)(xb + base) = o;
        float xv[4] = {v.x, v.y, v.z, v.w};
#pragma unroll
        for (int j = 0; j < 4; j++) {
#pragma unroll
          for (int e = 0; e < 8; e++) {
            float4 q = wq[j * 2 + (e >> 2)];
            float wv = (e & 3) == 0 ? q.x : (e & 3) == 1 ? q.y : (e & 3) == 2 ? q.z : q.w;
            acc[it][e] += xv[j] * wv;
          }
        }
      }
#pragma unroll
      for (int off = 32; off; off >>= 1)
#pragma unroll
        for (int it = 0; it < 4; it++)
#pragma unroll
          for (int e = 0; e < 8; e++)
            acc[it][e] += __shfl_down(acc[it][e], off);
      if (lane == 0) {
#pragma unroll
        for (int it = 0; it < 4; it++)
#pragma unroll
          for (int e = 0; e < 8; e++) sm.r.red[wave][it][e] = acc[it][e];
      }
      __syncthreads();
      if (tid < 4) {
        int t = tbase + tid;
        float lg[8];
#pragma unroll
        for (int e = 0; e < 8; e++)
          lg[e] = sm.r.red[0][tid][e] + sm.r.red[1][tid][e] + sm.r.red[2][tid][e] + sm.r.red[3][tid][e] + br[e];
        int i0 = 0; float v0 = lg[0];
#pragma unroll
        for (int e = 1; e < 8; e++) if (lg[e] > v0) { v0 = lg[e]; i0 = e; }
        int i1 = -1; float v1 = -3.4e38f;
#pragma unroll
        for (int e = 0; e < 8; e++) if (e != i0 && lg[e] > v1) { v1 = lg[e]; i1 = e; }
        out[(size_t)T_TOK * E_DIM + (size_t)t * 2 + 0] = (float)i0;
        out[(size_t)T_TOK * E_DIM + (size_t)t * 2 + 1] = (float)i1;
        t2[t * 2 + 0] = i0;
        t2[t * 2 + 1] = i1;
        atomicAdd(&sm.r.cnt[i0], 1);
        atomicAdd(&sm.r.cnt[i1], 1);
      }
      __syncthreads();                      // red reused next chunk
    }
    if (tid < 8) atomicAdd(&counts[tid], sm.r.cnt[tid]);
  } else {
    const float* src; u16* dst; int R, C, bx, by, e;
    if (blk < 256 + 3072) {
      int l = blk - 256;            // W1: R=E=1024, C=H=1536, grid (24,16,8)
      bx = l % 24; by = (l / 24) % 16; e = l / 384;
      R = E_DIM; C = H_DIM;
      src = W1 + (size_t)e * R * C; dst = w1t + (size_t)e * R * C;
    } else {
      int l = blk - (256 + 3072);   // W2: R=H=1536, C=E=1024, grid (16,24,8)
      bx = l % 16; by = (l / 16) % 24; e = l / 384;
      R = H_DIM; C = E_DIM;
      src = W2 + (size_t)e * R * C; dst = w2t + (size_t)e * R * C;
    }
    int c0 = bx * 64, r0 = by * 64;
    int tc = tid & 15, tr = tid >> 4;
    // load 4x4 fp32 block (rows r0+tr*4+j, cols c0+tc*4), transpose in regs,
    // write bf16 columns to LDS rows (c-index).
    {
      float4 v0 = *(const float4*)(src + (size_t)(r0 + tr * 4 + 0) * C + c0 + tc * 4);
      float4 v1 = *(const float4*)(src + (size_t)(r0 + tr * 4 + 1) * C + c0 + tc * 4);
      float4 v2 = *(const float4*)(src + (size_t)(r0 + tr * 4 + 2) * C + c0 + tc * 4);
      float4 v3 = *(const float4*)(src + (size_t)(r0 + tr * 4 + 3) * C + c0 + tc * 4);
      ushort4 w;
      w.x = f2bf(v0.x); w.y = f2bf(v1.x); w.z = f2bf(v2.x); w.w = f2bf(v3.x);
      *(ushort4*)(&sm.lt[tc * 4 + 0][tr * 4]) = w;
      w.x = f2bf(v0.y); w.y = f2bf(v1.y); w.z = f2bf(v2.y); w.w = f2bf(v3.y);
      *(ushort4*)(&sm.lt[tc * 4 + 1][tr * 4]) = w;
      w.x = f2bf(v0.z); w.y = f2bf(v1.z); w.z = f2bf(v2.z); w.w = f2bf(v3.z);
      *(ushort4*)(&sm.lt[tc * 4 + 2][tr * 4]) = w;
      w.x = f2bf(v0.w); w.y = f2bf(v1.w); w.z = f2bf(v2.w); w.w = f2bf(v3.w);
      *(ushort4*)(&sm.lt[tc * 4 + 3][tr * 4]) = w;
    }
    __syncthreads();
    // read 16 consecutive r for one output row (c-index), 2x ds_read_b128,
    // store 2x16B to dst[(c0+cc)][r0+rs..rs+15]
    {
      int cc = tid >> 2, rs = (tid & 3) * 16;
      frag_ab a = *(const frag_ab*)(&sm.lt[cc][rs]);
      frag_ab b = *(const frag_ab*)(&sm.lt[cc][rs + 8]);
      u16* drow = dst + (size_t)(c0 + cc) * R + r0 + rs;
      *(frag_ab*)(drow) = a;
      *(frag_ab*)(drow + 8) = b;
    }
  }
}

// fills clist and packs compact slot into t2: t2[t*2+k] = e | (slot<<3)
// Two-level ranking: LDS atomics for within-block rank, one global atomic
// per expert per block for the base. Slot order within an expert is an
// arbitrary bijection (nothing downstream depends on order).
__global__ __launch_bounds__(256) void k_fill(int* __restrict__ t2,
                                              const int* __restrict__ counts,
                                              int* __restrict__ curs,
                                              int* __restrict__ clist) {
  __shared__ int c8[8], base8[8];
  int tid = threadIdx.x;
  if (tid < 8) c8[tid] = 0;
  __syncthreads();

  int t = blockIdx.x * 256 + tid;
  int e0 = t2[t * 2 + 0] & 7;
  int e1 = t2[t * 2 + 1] & 7;
  int r0 = atomicAdd(&c8[e0], 1);
  int r1 = atomicAdd(&c8[e1], 1);
  __syncthreads();
  if (tid < 8) base8[tid] = atomicAdd(&curs[tid], c8[tid]);
  __syncthreads();

  int offs[8];
  {
    int run = 0;
#pragma unroll
    for (int e = 0; e < 8; e++) { offs[e] = run; run += counts[e]; }
  }
  int s0 = offs[e0] + base8[e0] + r0;
  int s1 = offs[e1] + base8[e1] + r1;
  clist[s0] = t;
  clist[s1] = t;
  t2[t * 2 + 0] = e0 | (s0 << 3);
  t2[t * 2 + 1] = e1 | (s1 << 3);
}

// ---- 256x256 8-wave GEMM, 1 barrier per K-iter (shared by gemm1/gemm2) ----
// A: [rows][KD] bf16 (gathered via clist when GATHER), B: [e][CN][KD] bf16 (B^T),
// C: [rows][CN] bf16. GELU => +bias then tanh-gelu (gemm1 epilogue).
// 512 thr = 8 waves (2M x 4N); per-wave out 128x64 = acc[8][4] frag_cd.
// LDS: lA[2][256*64] + lB[2][256*64] = 128 KiB (dynamic), XOR-8 col-group
// swizzle applied on the *source* address, gl2lds dst linear (guide rule 21).
// Per K-iter: __syncthreads (= vmcnt(0)+lgkm(0)+barrier: tile-t DMA issued a
// full iter ago is complete; all reads of buf c^1 were consumed by MFMAs so
// lgkm is already drained), then ONE region: stage tile t+1 (spread) + reads
// + MFMAs in program order -- compiler inserts minimal partial lgkm waits and
// overlaps quadrant q+1 reads under quadrant q MFMAs. No manual fences.

#define STG_A(cc, kk, ss) gl2lds16(gA[ss] + (kk), lA + (cc) * LDSTILE + ((ss) * 512 + tid) * 8)
#define STG_B(cc, kk, ss) gl2lds16(gB[ss] + (kk), lB + (cc) * LDSTILE + ((ss) * 512 + tid) * 8)
#define LDA8(qm) { const u16* cA_ = lA + c * LDSTILE; \
  _Pragma("unroll") for (int i_ = 0; i_ < 4; i_++) { \
    const u16* p_ = cA_ + (wm * 128 + ((qm) * 4 + i_) * 16 + mr) * 64; \
    Af[i_ * 2 + 0] = *(const frag_ab*)(p_ + g0); \
    Af[i_ * 2 + 1] = *(const frag_ab*)(p_ + g1); } }
#define LDB4(qn) { const u16* cB_ = lB + c * LDSTILE; \
  _Pragma("unroll") for (int j_ = 0; j_ < 2; j_++) { \
    const u16* p_ = cB_ + (wn * 64 + ((qn) * 2 + j_) * 16 + mr) * 64; \
    Bf[(qn) * 4 + j_ * 2 + 0] = *(const frag_ab*)(p_ + g0); \
    Bf[(qn) * 4 + j_ * 2 + 1] = *(const frag_ab*)(p_ + g1); } }
#define MMA16(qm, qn) { \
  _Pragma("unroll") for (int i_ = 0; i_ < 4; i_++) \
  _Pragma("unroll") for (int j_ = 0; j_ < 2; j_++) { \
    acc[(qm) * 4 + i_][(qn) * 2 + j_] = __builtin_amdgcn_mfma_f32_16x16x32_bf16(Af[i_ * 2 + 0], Bf[(qn) * 4 + j_ * 2 + 0], acc[(qm) * 4 + i_][(qn) * 2 + j_], 0, 0, 0); \
    acc[(qm) * 4 + i_][(qn) * 2 + j_] = __builtin_amdgcn_mfma_f32_16x16x32_bf16(Af[i_ * 2 + 1], Bf[(qn) * 4 + j_ * 2 + 1], acc[(qm) * 4 + i_][(qn) * 2 + j_], 0, 0, 0); } }

template<int KD, int CN, bool GELU, bool GATHER>
__global__ __launch_bounds__(512, 2) void k_gemm8(const u16* __restrict__ Ag,
                                                  const u16* __restrict__ Bw,
                                                  const float* __restrict__ bias,
                                                  u16* __restrict__ Cg,
                                                  const int* __restrict__ counts,
                                                  const int* __restrict__ clist) {
  constexpr int NTI = CN / 256;   // n-tiles
  constexpr int NKT = KD / 64;    // k-tiles
  static_assert((NKT & 1) == 0, "NKT must be even (buf0 prologue safety)");
  constexpr int MT  = 8;          // m-tiles per expert in grid (stride loop)
  constexpr int LDSTILE = 256 * 64;
  int bid = blockIdx.x;
  int e = bid & 7;                // XCD-pinned expert
  int slot = bid >> 3;            // 0..MT*NTI-1
  int cnt = counts[e];
  int mt = slot / NTI;
  int n0 = (slot % NTI) * 256;
  int off = 0;
#pragma unroll
  for (int j = 0; j < 8; j++) off += (j < e) ? counts[j] : 0;

  int tid = threadIdx.x;
  int lane = tid & 63, wave = tid >> 6;
  int wm = wave >> 2, wn = wave & 3;

  extern __shared__ __align__(16) u16 sm8[];
  u16* lA = sm8;                   // [2][256*64]
  u16* lB = sm8 + 2 * LDSTILE;     // [2][256*64]

  int q = lane >> 4, mr = lane & 15;
  int g0 = (q ^ (mr & 7)) * 8;        // swizzled LDS col offsets (u16 units)
  int g1 = g0 ^ (4 * 8);

  for (int m0 = mt * 256; m0 < cnt; m0 += MT * 256) {
    // staging source pointers: 4 A-loads + 4 B-loads per K-tile; source
    // col-group pre-swizzled, LDS dst linear (guide rule 21).
    const u16* gA[4];
    const u16* gB[4];
#pragma unroll
    for (int s = 0; s < 4; s++) {
      int idx = s * 512 + tid;       // 0..2047
      int r = idx >> 3;              // 0..255
      int cg = (idx & 7) ^ (r & 7);  // swizzled global col group
      int mrow = m0 + r; if (mrow >= cnt) mrow = cnt - 1;
      size_t arow;
      if constexpr (GATHER) arow = (size_t)clist[off + mrow] * KD;
      else                  arow = (size_t)(off + mrow) * KD;
      gA[s] = Ag + arow + cg * 8;
      gB[s] = Bw + (size_t)e * CN * KD + (size_t)(n0 + r) * KD + cg * 8;
    }

    frag_cd acc[8][4] = {};
    frag_ab Af[8], Bf[8];

    // prologue: full K-tile 0 into buf 0 (writes to buf0 are safe: buf0's
    // last reads (prior m-iter, t=NKT-2) are closed by t=NKT-1's barrier)
#pragma unroll
    for (int s = 0; s < 4; s++) STG_A(0, 0, s);
#pragma unroll
    for (int s = 0; s < 4; s++) STG_B(0, 0, s);

#pragma unroll 2
    for (int t = 0; t < NKT; t++) {
      int c = t & 1;
      int kn = (t + 1) * 64;
      bool pf = (t + 1) < NKT;
      // one barrier per K-iter: drains tile-t DMA (vmcnt0), fences LDS.
      __syncthreads();
      if (pf) { STG_A(c ^ 1, kn, 0); STG_A(c ^ 1, kn, 1); }
      LDA8(0); LDB4(0);
      if (pf) { STG_A(c ^ 1, kn, 2); STG_A(c ^ 1, kn, 3); }
      MMA16(0, 0);
      LDB4(1);
      if (pf) { STG_B(c ^ 1, kn, 0); STG_B(c ^ 1, kn, 1); }
      MMA16(0, 1);
      LDA8(1);
      if (pf) { STG_B(c ^ 1, kn, 2); STG_B(c ^ 1, kn, 3); }
      MMA16(1, 1);
      MMA16(1, 0);
    }

    // epilogue: C/D layout col=lane&15, row=(lane>>4)*4+reg
#pragma unroll
    for (int fi = 0; fi < 8; fi++) {
#pragma unroll
      for (int fj = 0; fj < 4; fj++) {
        int ng = n0 + wn * 64 + fj * 16 + mr;
        float bv = 0.f;
        if constexpr (GELU) bv = bias[e * CN + ng];
#pragma unroll
        for (int r = 0; r < 4; r++) {
          int mg = m0 + wm * 128 + fi * 16 + q * 4 + r;
          if (mg < cnt) {
            float v = acc[fi][fj][r];
            if constexpr (GELU) {
              v += bv;
              // tanh-GELU via sigmoid: v * sigma(1.5957691v + 0.0713548v^3)
              float z = v * (1.5957691216f + 0.0713548162f * v * v);
              v = v / (1.0f + __expf(-z));
            }
            Cg[(size_t)(off + mg) * CN + ng] = f2bf(v);
          }
        }
      }
    }
  }
}

// ---- combine: out[t] = 0.5*(y[slot0] + y[slot1] + b2[e0] + b2[e1]) ----
__global__ __launch_bounds__(256) void k_combine(const u16* __restrict__ y,
                                                 const float* __restrict__ b2,
                                                 const int* __restrict__ t2,
                                                 float* __restrict__ out) {
  int t = blockIdx.x;
  int c = threadIdx.x * 4;
  int v0 = t2[t * 2 + 0], v1 = t2[t * 2 + 1];
  int e0 = v0 & 7, s0 = v0 >> 3;
  int e1 = v1 & 7, s1 = v1 >> 3;
  ushort4 a = *(const ushort4*)(y + (size_t)s0 * E_DIM + c);
  ushort4 b = *(const ushort4*)(y + (size_t)s1 * E_DIM + c);
  float4 p0 = *(const float4*)(b2 + (size_t)e0 * E_DIM + c);
  float4 p1 = *(const float4*)(b2 + (size_t)e1 * E_DIM + c);
  float4 o;
  o.x = 0.5f * (bf2f(a.x) + bf2f(b.x) + p0.x + p1.x);
  o.y = 0.5f * (bf2f(a.y) + bf2f(b.y) + p0.y + p1.y);
  o.z = 0.5f * (bf2f(a.z) + bf2f(b.z) + p0.z + p1.z);
  o.w = 0.5f * (bf2f(a.w) + bf2f(b.w) + p0.w + p1.w);
  *(float4*)(out + (size_t)t * E_DIM + c) = o;
}

extern "C" void kernel_launch(void* const* d_in, const int* in_sizes, int n_in,
                              void* d_out, int out_size, void* d_ws, size_t ws_size,
                              hipStream_t stream) {
  (void)in_sizes; (void)n_in; (void)out_size; (void)ws_size;
  const float* x  = (const float*)d_in[0];
  const float* Wr = (const float*)d_in[1];
  const float* br = (const float*)d_in[2];
  const float* W1 = (const float*)d_in[3];
  const float* b1 = (const float*)d_in[4];
  const float* W2 = (const float*)d_in[5];
  const float* b2 = (const float*)d_in[6];
  float* out = (float*)d_out;
  char* ws = (char*)d_ws;

  int* meta  = (int*)ws;                  // counts@0, cursors@+16 ints
  int* t2    = (int*)(ws + O_T2);
  int* clist = (int*)(ws + O_CLIST);
  u16* xb    = (u16*)(ws + O_XB);
  u16* w1t   = (u16*)(ws + O_W1T);
  u16* w2t   = (u16*)(ws + O_W2T);
  u16* hb    = (u16*)(ws + O_HB);
  u16* y     = (u16*)(ws + O_Y);          // overlays xb+w1t (dead after gemm1)

  // opt-in to 128 KiB dynamic LDS (immediate host call, not graph-captured)
  static int attr_once = [] {
    (void)hipFuncSetAttribute(reinterpret_cast<const void*>(&k_gemm8<E_DIM, H_DIM, true, true>),
                              hipFuncAttributeMaxDynamicSharedMemorySize, 131072);
    (void)hipFuncSetAttribute(reinterpret_cast<const void*>(&k_gemm8<H_DIM, E_DIM, false, false>),
                              hipFuncAttributeMaxDynamicSharedMemorySize, 131072);
    return 0;
  }();
  (void)attr_once;

  hipMemsetAsync(ws, 0, 128, stream);     // zero counts + cursors

  k_prep<<<dim3(256 + 3072 + 3072), 256, 0, stream>>>(x, Wr, br, W1, W2, out, xb, w1t, w2t, t2, meta);
  k_fill<<<dim3(T_TOK / 256), 256, 0, stream>>>(t2, meta, meta + 16, clist);
  // gemm1: M=cnt[e] (~2048 -> 8 m-tiles), N=1536 (6 n-tiles), K=1024
  k_gemm8<E_DIM, H_DIM, true, true><<<dim3(8 * 8 * 6), 512, 131072, stream>>>(
      xb, w1t, b1, hb, meta, clist);
  // gemm2: N=1024 (4 n-tiles), K=1536
  k_gemm8<H_DIM, E_DIM, false, false><<<dim3(8 * 8 * 4), 512, 131072, stream>>>(
      hb, w2t, nullptr, y, meta, nullptr);
  k_combine<<<dim3(T_TOK), 256, 0, stream>>>(y, b2, t2, out);
}